// Round 6
// baseline (583.506 us; speedup 1.0000x reference)
//
#include <hip/hip_runtime.h>

// HNM discriminative loss, MI355X — R9.
// predict (4,32,512,1024) f32, target (4,512,1024) i32 -> scalar f32.
// R9: R8 pinned k_accum~155 (plain-RMW beat atomics 429->155 but missed the
// 55-90 model) and locked the mask-FMA VALU model (57 ops/elem = 195us ~= R6's
// 213 — dead end). Random per-lane classes make the stride-21 histogram a
// random 64->32 bank toss (~4-8-way, m136 1.6-2.9x) on EVERY access.
// Fix 1: bank-per-lane layout hist[wave][class][lane] — lane l always hits
//   bank l%32, 2 lanes/bank = free. DS -> ~21us; k_accum -> HBM-bound.
// Fix 2: k_var rewrite — no 72KB staging; 32 independent coalesced float4
//   loads/thread (32KB in flight/wave), centers transposed [19][36] so each
//   px's 32 ctr values = 8 ds_read_b128; sq/pos via bank-per-lane plain RMW.
// fill (161us) is harness ws-poison: fixed overhead, also proves 6.7TB/s.

#define K_CLS 19
#define C_CH 32
#define HW_SHIFT 19            // H*W = 512*1024 = 2^19
#define HW_SIZE (1 << HW_SHIFT)
#define EPSF 1e-12f
#define THEA_F 0.5f
#define TWO_DELTA 3.0f
#define MIN_PIX 20.0f

// ---- ws float layout (no global atomics; every cell written before read) --
#define OFF_PSUM 0                       // [ch][64 slots][20] = 40960
#define OFF_PCNT 40960                   // [64 slots][20] = 1280
#define OFF_RED  42240                   // 608 sums + 19 counts (pad 640)
#define OFF_VPART 42880                  // [2048 blk][64]: 19 sq + 19 pos
#define WS_FLOATS (OFF_VPART + 2048 * 64)

__device__ __forceinline__ void atomAddF(float* p, float v) {
  unsafeAtomicAdd(p, v);       // cold paths only (k_final small reduces)
}

// ---- Pass 1 v6: bank-per-lane private histogram, plain DS RMW ------------
// Blocks 0..2047: (plane, 16 slabs) feature sums. Blocks 2048..2111: counts.
// hist[w][k][lane]: lane l always bank l%32 (2 lanes/bank = free, m136).
__global__ __launch_bounds__(256) void k_accum(
    const float* __restrict__ pred, const int* __restrict__ tgt,
    float* __restrict__ ws)
{
  __shared__ float s_hist[4][20][64];           // 20480 B -> 7 blocks/CU
  __shared__ float s_w[4][20];
  const int t = threadIdx.x;
  const int w = t >> 6;
  const int lane = t & 63;
  float* col = &s_hist[w][0][lane];             // col[k<<6] = bin k
#pragma unroll
  for (int k = 0; k < 20; ++k) col[k << 6] = 0.f;
  // thread-private column until flush: no barrier needed

  if (blockIdx.x < 2048) {
    // ---- feature-sum block: plane = n*32+ch, slab = 32K px ----
    const int plane = blockIdx.x >> 4;       // 0..127
    const int slab  = blockIdx.x & 15;       // 0..15
    const int n_idx = plane >> 5;
    const int ch    = plane & 31;
    const float* pbase = pred + (((size_t)plane) << HW_SHIFT) + ((size_t)slab << 15);
    const int*   tbase = tgt  + (((size_t)n_idx) << HW_SHIFT) + ((size_t)slab << 15);

    float4 vA = *reinterpret_cast<const float4*>(pbase + t * 4);
    int4   cA = *reinterpret_cast<const int4*>(tbase + t * 4);
#pragma unroll 1
    for (int it = 0; it < 32; ++it) {
      float4 vB; int4 cB;
      if (it + 1 < 32) {
        vB = *reinterpret_cast<const float4*>(pbase + (it + 1) * 1024 + t * 4);
        cB = *reinterpret_cast<const int4*>(tbase + (it + 1) * 1024 + t * 4);
      }
      const float x[4] = {vA.x, vA.y, vA.z, vA.w};
      const int   s[4] = {cA.x, cA.y, cA.z, cA.w};
#pragma unroll
      for (int i = 0; i < 4; ++i) {
        const int slot = min((unsigned)s[i], (unsigned)K_CLS);  // 255 -> junk 19
        col[slot << 6] += x[i];            // ds_read+v_add+ds_write, bank l%32
      }
      vA = vB; cA = cB;
    }

    // flush: own column -> regs -> wave shfl reduce -> 4-wave combine -> ws
    float acc[K_CLS];
#pragma unroll
    for (int k = 0; k < K_CLS; ++k) acc[k] = col[k << 6];
#pragma unroll
    for (int k = 0; k < K_CLS; ++k) {
      float s = acc[k];
#pragma unroll
      for (int m = 1; m < 64; m <<= 1) s += __shfl_xor(s, m, 64);
      acc[k] = s;
    }
#pragma unroll
    for (int k = 0; k < K_CLS; ++k)
      if (lane == k) s_w[w][k] = acc[k];       // static index: no scratch
    __syncthreads();
    if (t < K_CLS) {
      const int slot = n_idx * 16 + slab;      // 0..63
      ws[OFF_PSUM + ch * (64 * 20) + slot * 20 + t] =
          s_w[0][t] + s_w[1][t] + s_w[2][t] + s_w[3][t];
    }
  } else {
    // ---- count block (reads tgt only) ----
    const int idx = blockIdx.x - 2048;       // 0..63
    const int n_idx = idx >> 4;
    const int slab  = idx & 15;
    const int* tbase = tgt + (((size_t)n_idx) << HW_SHIFT) + ((size_t)slab << 15);

#pragma unroll 1
    for (int it = 0; it < 32; ++it) {
      const int4 c4 = *reinterpret_cast<const int4*>(tbase + it * 1024 + t * 4);
      const int s[4] = {c4.x, c4.y, c4.z, c4.w};
#pragma unroll
      for (int i = 0; i < 4; ++i) {
        const int slot = min((unsigned)s[i], (unsigned)K_CLS);
        col[slot << 6] += 1.f;
      }
    }

    float acc[K_CLS];
#pragma unroll
    for (int k = 0; k < K_CLS; ++k) acc[k] = col[k << 6];
#pragma unroll
    for (int k = 0; k < K_CLS; ++k) {
      float s = acc[k];
#pragma unroll
      for (int m = 1; m < 64; m <<= 1) s += __shfl_xor(s, m, 64);
      acc[k] = s;
    }
#pragma unroll
    for (int k = 0; k < K_CLS; ++k)
      if (lane == k) s_w[w][k] = acc[k];
    __syncthreads();
    if (t < K_CLS) {
      const int slot = n_idx * 16 + slab;
      ws[OFF_PCNT + slot * 20 + t] = s_w[0][t] + s_w[1][t] + s_w[2][t] + s_w[3][t];
    }
  }
}

// ---- Reduce 64 slots -> 627 totals (single small block) -------------------
__global__ __launch_bounds__(256) void k_reduce(float* __restrict__ ws)
{
  const int t = threadIdx.x;
  for (int o = t; o < C_CH * K_CLS; o += 256) {
    const int ch = o / K_CLS, k = o - ch * K_CLS;
    float a = 0.f;
#pragma unroll 4
    for (int s = 0; s < 64; ++s) a += ws[OFF_PSUM + ch * (64 * 20) + s * 20 + k];
    ws[OFF_RED + o] = a;
  }
  if (t < K_CLS) {
    float a = 0.f;
#pragma unroll 4
    for (int s = 0; s < 64; ++s) a += ws[OFF_PCNT + s * 20 + t];
    ws[OFF_RED + C_CH * K_CLS + t] = a;
  }
}

// ---- Pass 2 v4: register loads + transposed-ctr b128 gather ---------------
// Block = 1024 px (4 waves x 256), thread = 4 adjacent px. 32 independent
// coalesced float4 loads (32KB in flight/wave). ctrT[19][36]: per px the 32
// ctr values are 8 ds_read_b128. sq/pos: bank-per-lane plain RMW [20][256].
__global__ __launch_bounds__(256) void k_var(
    const float* __restrict__ pred, const int* __restrict__ tgt,
    float* __restrict__ ws)
{
  __shared__ float s_ctrT[K_CLS][36];       // stride 36: 16B-aligned rows
  __shared__ float s_sq[20][256];           // 20 KB, column t exclusive
  __shared__ float s_pos[20][256];          // 20 KB
  __shared__ float s_w[4][20];
  __shared__ float s_w2[4][20];

  const int t = threadIdx.x;
  const int w = t >> 6;
  const int lane = t & 63;

  for (int i = t; i < C_CH * K_CLS; i += 256) {
    const int c = i / K_CLS, s = i - c * K_CLS;
    s_ctrT[s][c] = ws[OFF_RED + i] / fmaxf(ws[OFF_RED + C_CH * K_CLS + s], 1.f);
  }
  for (int i = t; i < 20 * 256; i += 256) {
    (&s_sq[0][0])[i] = 0.f;
    (&s_pos[0][0])[i] = 0.f;
  }
  __syncthreads();

  const size_t P0 = (size_t)blockIdx.x * 1024;
  const int n_idx = (int)(P0 >> HW_SHIFT);
  const int hw = (int)(P0 & (HW_SIZE - 1)) + w * 256 + lane * 4;
  const float* pb = pred + (((size_t)(n_idx * C_CH)) << HW_SHIFT) + hw;

  const int4 c4 = *reinterpret_cast<const int4*>(tgt + (((size_t)n_idx) << HW_SHIFT) + hw);
  int  sc[4] = {c4.x, c4.y, c4.z, c4.w};
  bool vl[4];
#pragma unroll
  for (int j = 0; j < 4; ++j) { vl[j] = (unsigned)sc[j] < K_CLS; if (!vl[j]) sc[j] = 0; }

  // 32 independent coalesced loads (1 KB/wave-instr), all issued up front
  float4 xv[C_CH];
#pragma unroll
  for (int c = 0; c < C_CH; ++c)
    xv[c] = *reinterpret_cast<const float4*>(pb + ((size_t)c << HW_SHIFT));

  float d2[4] = {0.f, 0.f, 0.f, 0.f};
#pragma unroll
  for (int j = 0; j < 4; ++j) {
    const int s = sc[j];
#pragma unroll
    for (int cb = 0; cb < 8; ++cb) {      // 8 x ds_read_b128 per px
      const float4 g = *reinterpret_cast<const float4*>(&s_ctrT[s][cb * 4]);
      const float x0 = ((const float*)&xv[cb * 4 + 0])[j];
      const float x1 = ((const float*)&xv[cb * 4 + 1])[j];
      const float x2 = ((const float*)&xv[cb * 4 + 2])[j];
      const float x3 = ((const float*)&xv[cb * 4 + 3])[j];
      const float e0 = g.x - x0, e1 = g.y - x1, e2 = g.z - x2, e3 = g.w - x3;
      d2[j] = fmaf(e0, e0, d2[j]);
      d2[j] = fmaf(e1, e1, d2[j]);
      d2[j] = fmaf(e2, e2, d2[j]);
      d2[j] = fmaf(e3, e3, d2[j]);
    }
  }

#pragma unroll
  for (int j = 0; j < 4; ++j) {
    if (vl[j]) {
      const float r = sqrtf(d2[j] + EPSF) - THEA_F;
      if (r > 0.f) {
        s_sq[sc[j]][t]  += r * r;          // plain RMW, own column t
        s_pos[sc[j]][t] += 1.f;
      }
    }
  }

  __syncthreads();
  // block reduce: thread t owns column t; shfl across wave per class
  float asq[K_CLS], apos[K_CLS];
#pragma unroll
  for (int k = 0; k < K_CLS; ++k) { asq[k] = s_sq[k][t]; apos[k] = s_pos[k][t]; }
#pragma unroll
  for (int k = 0; k < K_CLS; ++k) {
    float a = asq[k], b = apos[k];
#pragma unroll
    for (int m = 1; m < 64; m <<= 1) {
      a += __shfl_xor(a, m, 64);
      b += __shfl_xor(b, m, 64);
    }
    asq[k] = a; apos[k] = b;
  }
#pragma unroll
  for (int k = 0; k < K_CLS; ++k)
    if (lane == k) { s_w[w][k] = asq[k]; s_w2[w][k] = apos[k]; }
  __syncthreads();
  if (t < K_CLS) {
    float* vp = ws + OFF_VPART + (size_t)blockIdx.x * 64;
    vp[t]         = s_w[0][t] + s_w[1][t] + s_w[2][t] + s_w[3][t];
    vp[K_CLS + t] = s_w2[0][t] + s_w2[1][t] + s_w2[2][t] + s_w2[3][t];
  }
}

// ---- Finalize: reduce vparts, then loss_var + loss_dis + 0.001*loss_reg ---
__global__ __launch_bounds__(1024) void k_final(
    float* __restrict__ ws, float* __restrict__ out, int nb)
{
  __shared__ float s_ctr[C_CH * K_CLS];
  __shared__ float s_valid[K_CLS];
  __shared__ float s_sq[K_CLS];
  __shared__ float s_pos[K_CLS];
  __shared__ float s_red[3];
  __shared__ float s_ncls;
  const int t = threadIdx.x;
  if (t < 3) s_red[t] = 0.f;
  if (t < K_CLS) { s_sq[t] = 0.f; s_pos[t] = 0.f; }
  if (t < K_CLS) s_valid[t] = (ws[OFF_RED + C_CH * K_CLS + t] > MIN_PIX) ? 1.f : 0.f;
  for (int i = t; i < C_CH * K_CLS; i += 1024) {
    const int k = i % K_CLS;
    s_ctr[i] = ws[OFF_RED + i] / fmaxf(ws[OFF_RED + C_CH * K_CLS + k], 1.f);
  }
  __syncthreads();

  {
    const int o = t & 63, slice = t >> 6;
    if (o < 2 * K_CLS) {
      float a = 0.f;
      for (int b = slice; b < nb; b += 16)
        a += ws[OFF_VPART + (size_t)b * 64 + o];
      atomAddF(o < K_CLS ? &s_sq[o] : &s_pos[o - K_CLS], a);
    }
  }
  __syncthreads();

  if (t == 0) {
    float n = 0.f;
    for (int k = 0; k < K_CLS; ++k) n += s_valid[k];
    s_ncls = fmaxf(n, 1.f);
  }
  if (t < K_CLS && s_valid[t] > 0.f) {
    atomAddF(&s_red[0], s_sq[t] / fmaxf(s_pos[t], 1.f));
    float nn = 0.f;
#pragma unroll
    for (int ch = 0; ch < C_CH; ++ch) {
      const float cv = s_ctr[ch * K_CLS + t];
      nn = fmaf(cv, cv, nn);
    }
    atomAddF(&s_red[2], sqrtf(nn + EPSF));
  }
  if (t < K_CLS * K_CLS) {
    const int a = t / K_CLS, b = t - (t / K_CLS) * K_CLS;
    if (a != b && s_valid[a] > 0.f && s_valid[b] > 0.f) {
      float dd = 0.f;
#pragma unroll
      for (int ch = 0; ch < C_CH; ++ch) {
        const float df = s_ctr[ch * K_CLS + a] - s_ctr[ch * K_CLS + b];
        dd = fmaf(df, df, dd);
      }
      const float dist = sqrtf(dd + EPSF);
      const float d = fmaxf(TWO_DELTA - dist, 0.f);
      if (d > 0.f) atomAddF(&s_red[1], d * d);
    }
  }
  __syncthreads();
  if (t == 0) {
    const float n = s_ncls;
    out[0] = s_red[0] / n
           + s_red[1] / fmaxf(n * (n - 1.f), 1.f)
           + 0.001f * s_red[2] / n;
  }
}

extern "C" void kernel_launch(void* const* d_in, const int* in_sizes, int n_in,
                              void* d_out, int out_size, void* d_ws, size_t ws_size,
                              hipStream_t stream) {
  const float* pred = (const float*)d_in[0];
  const int*   tgt  = (const int*)d_in[1];
  float* ws  = (float*)d_ws;
  float* out = (float*)d_out;
  const int P = in_sizes[1];            // n*h*w = 2097152
  const int nBlocksVar = P / 1024;      // 2048

  k_accum <<<2048 + 64, 256, 0, stream>>>(pred, tgt, ws);  // 2048 sum + 64 count
  k_reduce<<<1, 256, 0, stream>>>(ws);
  k_var   <<<nBlocksVar, 256, 0, stream>>>(pred, tgt, ws);
  k_final <<<1, 1024, 0, stream>>>(ws, out, nBlocksVar);
}

// Round 7
// 449.596 us; speedup vs baseline: 1.2978x; 1.2978x over previous
//
#include <hip/hip_runtime.h>

// HNM discriminative loss, MI355X — R10.
// predict (4,32,512,1024) f32, target (4,512,1024) i32 -> scalar f32.
// R10: R9 regressed (583) but bounded every kernel <159us -> the single-block
// tail reducers (k_reduce 64-deep strided latency chains ~40-65us, k_final
// vpart loop ~35-50us) have been hiding under the 159us ws-poison fill since
// R4. Fix 1 (tails): k_reduce -> 627 one-wave blocks; new k_vred (38 blocks)
// pre-reduces sq/pos; k_final reads 38 scalars. Fix 2 (accum): dual-parity
// histograms A/B (disjoint __shared__ arrays) so the compiler can overlap
// RMW chains of adjacent elements (alias-free), halving lgkmcnt stalls;
// 19-slot columns (invalid lanes add 0.0 to slot 18) keep LDS 39KB = 4
// blocks/CU. k_var reverted to the proven R8 staged version (1024 blocks).

#define K_CLS 19
#define C_CH 32
#define HW_SHIFT 19            // H*W = 512*1024 = 2^19
#define HW_SIZE (1 << HW_SHIFT)
#define EPSF 1e-12f
#define THEA_F 0.5f
#define TWO_DELTA 3.0f
#define MIN_PIX 20.0f

// ---- ws float layout (no global atomics; every cell written before read) --
#define OFF_PSUM 0                       // [ch][64 slots][20] = 40960
#define OFF_PCNT 40960                   // [64 slots][20] = 1280
#define OFF_RED  42240                   // 608 sums + 19 counts (pad 640)
#define OFF_VRED 42880                   // 38 reduced sq/pos (pad 64)
#define OFF_VPART 42944                  // [1024 blk][64]: 19 sq + 19 pos
#define WS_FLOATS (OFF_VPART + 1024 * 64)

typedef const unsigned int __attribute__((address_space(1)))* GP;
typedef unsigned int __attribute__((address_space(3)))* LP;

__device__ __forceinline__ void atomAddF(float* p, float v) {
  unsafeAtomicAdd(p, v);       // cold paths only
}

// ---- Pass 1 v7: dual-parity bank-per-lane histograms, plain DS RMW -------
// Blocks 0..2047: (plane, 16 slabs) feature sums. Blocks 2048..2111: counts.
// Elements 0,2 -> histA; 1,3 -> histB (disjoint arrays: compiler may overlap
// the RMW chains). Column lane l always hits bank l%32 (2 lanes/bank: free).
__global__ __launch_bounds__(256) void k_accum(
    const float* __restrict__ pred, const int* __restrict__ tgt,
    float* __restrict__ ws)
{
  __shared__ float sA[4][K_CLS][64];            // 19456 B
  __shared__ float sB[4][K_CLS][64];            // 19456 B  -> 4 blocks/CU
  __shared__ float s_w[4][20];
  const int t = threadIdx.x;
  const int w = t >> 6;
  const int lane = t & 63;
  float* colA = &sA[w][0][lane];                // colA[k<<6] = bin k
  float* colB = &sB[w][0][lane];
#pragma unroll
  for (int k = 0; k < K_CLS; ++k) { colA[k << 6] = 0.f; colB[k << 6] = 0.f; }
  // thread-private columns until flush: no barrier needed

  if (blockIdx.x < 2048) {
    // ---- feature-sum block: plane = n*32+ch, slab = 32K px ----
    const int plane = blockIdx.x >> 4;       // 0..127
    const int slab  = blockIdx.x & 15;       // 0..15
    const int n_idx = plane >> 5;
    const int ch    = plane & 31;
    const float* pbase = pred + (((size_t)plane) << HW_SHIFT) + ((size_t)slab << 15);
    const int*   tbase = tgt  + (((size_t)n_idx) << HW_SHIFT) + ((size_t)slab << 15);

    float4 vA = *reinterpret_cast<const float4*>(pbase + t * 4);
    int4   cA = *reinterpret_cast<const int4*>(tbase + t * 4);
#pragma unroll 1
    for (int it = 0; it < 32; ++it) {
      float4 vB; int4 cB;
      if (it + 1 < 32) {
        vB = *reinterpret_cast<const float4*>(pbase + (it + 1) * 1024 + t * 4);
        cB = *reinterpret_cast<const int4*>(tbase + (it + 1) * 1024 + t * 4);
      }
      const float x[4] = {vA.x, vA.y, vA.z, vA.w};
      const int   s[4] = {cA.x, cA.y, cA.z, cA.w};
      // invalid (255) -> slot 18, add 0.0 (harmless); valid class fits 0..18
      const int   k0 = min((unsigned)s[0], 18u), k1 = min((unsigned)s[1], 18u);
      const int   k2 = min((unsigned)s[2], 18u), k3 = min((unsigned)s[3], 18u);
      const float v0 = ((unsigned)s[0] < K_CLS) ? x[0] : 0.f;
      const float v1 = ((unsigned)s[1] < K_CLS) ? x[1] : 0.f;
      const float v2 = ((unsigned)s[2] < K_CLS) ? x[2] : 0.f;
      const float v3 = ((unsigned)s[3] < K_CLS) ? x[3] : 0.f;
      colA[k0 << 6] += v0;
      colB[k1 << 6] += v1;
      colA[k2 << 6] += v2;
      colB[k3 << 6] += v3;
      vA = vB; cA = cB;
    }

    float acc[K_CLS];
#pragma unroll
    for (int k = 0; k < K_CLS; ++k) acc[k] = colA[k << 6] + colB[k << 6];
#pragma unroll
    for (int k = 0; k < K_CLS; ++k) {
      float s = acc[k];
#pragma unroll
      for (int m = 1; m < 64; m <<= 1) s += __shfl_xor(s, m, 64);
      acc[k] = s;
    }
#pragma unroll
    for (int k = 0; k < K_CLS; ++k)
      if (lane == k) s_w[w][k] = acc[k];       // static index: no scratch
    __syncthreads();
    if (t < K_CLS) {
      const int slot = n_idx * 16 + slab;      // 0..63
      ws[OFF_PSUM + ch * (64 * 20) + slot * 20 + t] =
          s_w[0][t] + s_w[1][t] + s_w[2][t] + s_w[3][t];
    }
  } else {
    // ---- count block (reads tgt only) ----
    const int idx = blockIdx.x - 2048;       // 0..63
    const int n_idx = idx >> 4;
    const int slab  = idx & 15;
    const int* tbase = tgt + (((size_t)n_idx) << HW_SHIFT) + ((size_t)slab << 15);

#pragma unroll 1
    for (int it = 0; it < 32; ++it) {
      const int4 c4 = *reinterpret_cast<const int4*>(tbase + it * 1024 + t * 4);
      const int s[4] = {c4.x, c4.y, c4.z, c4.w};
      const int k0 = min((unsigned)s[0], 18u), k1 = min((unsigned)s[1], 18u);
      const int k2 = min((unsigned)s[2], 18u), k3 = min((unsigned)s[3], 18u);
      colA[k0 << 6] += ((unsigned)s[0] < K_CLS) ? 1.f : 0.f;
      colB[k1 << 6] += ((unsigned)s[1] < K_CLS) ? 1.f : 0.f;
      colA[k2 << 6] += ((unsigned)s[2] < K_CLS) ? 1.f : 0.f;
      colB[k3 << 6] += ((unsigned)s[3] < K_CLS) ? 1.f : 0.f;
    }

    float acc[K_CLS];
#pragma unroll
    for (int k = 0; k < K_CLS; ++k) acc[k] = colA[k << 6] + colB[k << 6];
#pragma unroll
    for (int k = 0; k < K_CLS; ++k) {
      float s = acc[k];
#pragma unroll
      for (int m = 1; m < 64; m <<= 1) s += __shfl_xor(s, m, 64);
      acc[k] = s;
    }
#pragma unroll
    for (int k = 0; k < K_CLS; ++k)
      if (lane == k) s_w[w][k] = acc[k];
    __syncthreads();
    if (t < K_CLS) {
      const int slot = n_idx * 16 + slab;
      ws[OFF_PCNT + slot * 20 + t] = s_w[0][t] + s_w[1][t] + s_w[2][t] + s_w[3][t];
    }
  }
}

// ---- Reduce: 627 one-wave blocks, lane = slot ----------------------------
__global__ __launch_bounds__(64) void k_reduce(float* __restrict__ ws)
{
  const int o = blockIdx.x;            // 0..626
  const int lane = threadIdx.x;        // 0..63 = slot
  float a;
  if (o < C_CH * K_CLS) {
    const int ch = o / K_CLS, k = o - ch * K_CLS;
    a = ws[OFF_PSUM + ch * (64 * 20) + lane * 20 + k];
  } else {
    a = ws[OFF_PCNT + lane * 20 + (o - C_CH * K_CLS)];
  }
#pragma unroll
  for (int m = 1; m < 64; m <<= 1) a += __shfl_xor(a, m, 64);
  if (lane == 0) ws[OFF_RED + o] = a;
}

// ---- Pass 2 (R8-proven): global_load_lds staged, px-per-lane windows ------
__global__ __launch_bounds__(256) void k_var(
    const float* __restrict__ pred, const int* __restrict__ tgt,
    float* __restrict__ ws)
{
  __shared__ float s_buf[4][2][C_CH][64];   // 64 KB
  __shared__ int   s_cls[4][2][256];        // 8 KB (only first 64 ints used)
  __shared__ float s_ctr[C_CH][K_CLS];
  __shared__ float s_sq[K_CLS];
  __shared__ float s_pos[K_CLS];

  const int t = threadIdx.x;
  const int w = t >> 6;
  const int lane = t & 63;

  for (int i = t; i < C_CH * K_CLS; i += 256) {
    const int k = i % K_CLS;
    (&s_ctr[0][0])[i] = ws[OFF_RED + i] / fmaxf(ws[OFF_RED + C_CH * K_CLS + k], 1.f);
  }
  if (t < K_CLS) { s_sq[t] = 0.f; s_pos[t] = 0.f; }
  __syncthreads();

  const size_t P0 = (size_t)blockIdx.x * 2048;
  const int n_idx = (int)(P0 >> HW_SHIFT);
  const int hw0 = (int)(P0 & (HW_SIZE - 1));
  const int qch = lane >> 4;
  const int qpx = (lane & 15) * 4;

#define STAGE(h, j)                                                           \
  {                                                                           \
    const int pw = hw0 + w * 512 + (j) * 64;                                  \
    _Pragma("unroll")                                                         \
    for (int q = 0; q < 8; ++q) {                                             \
      const int c = q * 4 + qch;                                              \
      const float* gp = pred + (((size_t)(n_idx * C_CH + c)) << HW_SHIFT)     \
                        + pw + qpx;                                           \
      __builtin_amdgcn_global_load_lds((GP)gp, (LP)&s_buf[w][h][0][0] + q * 256, \
                                       16, 0, 0);                             \
    }                                                                         \
    const int* gt = tgt + (((size_t)n_idx) << HW_SHIFT) + pw + qpx;           \
    __builtin_amdgcn_global_load_lds((GP)gt, (LP)&s_cls[w][h][0], 16, 0, 0);  \
  }

  float res8[8];
  int   cls8[8];

  STAGE(0, 0)
#pragma unroll 1
  for (int j = 0; j < 8; ++j) {
    const int h = j & 1;
    if (j < 7) {
      STAGE(h ^ 1, j + 1)
      asm volatile("s_waitcnt vmcnt(9)" ::: "memory");
    } else {
      asm volatile("s_waitcnt vmcnt(0)" ::: "memory");
    }
    __builtin_amdgcn_sched_barrier(0);

    const int ci = s_cls[w][h][lane];
    const bool vld = (unsigned)ci < K_CLS;
    const int sc = vld ? ci : 0;
    float d2 = 0.f;
#pragma unroll
    for (int c = 0; c < C_CH; ++c) {
      const float x = s_buf[w][h][c][lane];
      const float d = s_ctr[c][sc] - x;
      d2 = fmaf(d, d, d2);
    }
    res8[j] = d2;
    cls8[j] = vld ? ci : -1;
  }

#pragma unroll
  for (int j = 0; j < 8; ++j) {
    if (cls8[j] >= 0) {
      const float r = sqrtf(res8[j] + EPSF) - THEA_F;
      if (r > 0.f) { atomAddF(&s_sq[cls8[j]], r * r); atomAddF(&s_pos[cls8[j]], 1.f); }
    }
  }

  __syncthreads();
  if (t < K_CLS) {
    float* vp = ws + OFF_VPART + (size_t)blockIdx.x * 64;
    vp[t]         = s_sq[t];
    vp[K_CLS + t] = s_pos[t];
  }
#undef STAGE
}

// ---- Pre-reduce sq/pos: 38 blocks x 256 threads ---------------------------
__global__ __launch_bounds__(256) void k_vred(float* __restrict__ ws)
{
  const int o = blockIdx.x;            // 0..37 (sq: 0..18, pos: 19..37)
  const int t = threadIdx.x;
  float a = 0.f;
#pragma unroll
  for (int r = 0; r < 4; ++r)
    a += ws[OFF_VPART + (size_t)(t + r * 256) * 64 + o];
#pragma unroll
  for (int m = 1; m < 64; m <<= 1) a += __shfl_xor(a, m, 64);
  __shared__ float s[4];
  if ((t & 63) == 0) s[t >> 6] = a;
  __syncthreads();
  if (t == 0) ws[OFF_VRED + o] = s[0] + s[1] + s[2] + s[3];
}

// ---- Finalize: loss_var + loss_dis + 0.001*loss_reg -----------------------
__global__ __launch_bounds__(1024) void k_final(
    float* __restrict__ ws, float* __restrict__ out)
{
  __shared__ float s_ctr[C_CH * K_CLS];
  __shared__ float s_valid[K_CLS];
  __shared__ float s_red[3];
  __shared__ float s_ncls;
  const int t = threadIdx.x;
  if (t < 3) s_red[t] = 0.f;
  if (t < K_CLS) s_valid[t] = (ws[OFF_RED + C_CH * K_CLS + t] > MIN_PIX) ? 1.f : 0.f;
  for (int i = t; i < C_CH * K_CLS; i += 1024) {
    const int k = i % K_CLS;
    s_ctr[i] = ws[OFF_RED + i] / fmaxf(ws[OFF_RED + C_CH * K_CLS + k], 1.f);
  }
  __syncthreads();

  if (t == 0) {
    float n = 0.f;
    for (int k = 0; k < K_CLS; ++k) n += s_valid[k];
    s_ncls = fmaxf(n, 1.f);
  }
  if (t < K_CLS && s_valid[t] > 0.f) {
    const float sq  = ws[OFF_VRED + t];
    const float pos = ws[OFF_VRED + K_CLS + t];
    atomAddF(&s_red[0], sq / fmaxf(pos, 1.f));
    float nn = 0.f;
#pragma unroll
    for (int ch = 0; ch < C_CH; ++ch) {
      const float cv = s_ctr[ch * K_CLS + t];
      nn = fmaf(cv, cv, nn);
    }
    atomAddF(&s_red[2], sqrtf(nn + EPSF));
  }
  if (t < K_CLS * K_CLS) {
    const int a = t / K_CLS, b = t - (t / K_CLS) * K_CLS;
    if (a != b && s_valid[a] > 0.f && s_valid[b] > 0.f) {
      float dd = 0.f;
#pragma unroll
      for (int ch = 0; ch < C_CH; ++ch) {
        const float df = s_ctr[ch * K_CLS + a] - s_ctr[ch * K_CLS + b];
        dd = fmaf(df, df, dd);
      }
      const float dist = sqrtf(dd + EPSF);
      const float d = fmaxf(TWO_DELTA - dist, 0.f);
      if (d > 0.f) atomAddF(&s_red[1], d * d);
    }
  }
  __syncthreads();
  if (t == 0) {
    const float n = s_ncls;
    out[0] = s_red[0] / n
           + s_red[1] / fmaxf(n * (n - 1.f), 1.f)
           + 0.001f * s_red[2] / n;
  }
}

extern "C" void kernel_launch(void* const* d_in, const int* in_sizes, int n_in,
                              void* d_out, int out_size, void* d_ws, size_t ws_size,
                              hipStream_t stream) {
  const float* pred = (const float*)d_in[0];
  const int*   tgt  = (const int*)d_in[1];
  float* ws  = (float*)d_ws;
  float* out = (float*)d_out;
  const int P = in_sizes[1];            // n*h*w = 2097152
  const int nBlocksVar = P / 2048;      // 1024

  k_accum <<<2048 + 64, 256, 0, stream>>>(pred, tgt, ws);  // 2048 sum + 64 count
  k_reduce<<<C_CH * K_CLS + K_CLS, 64, 0, stream>>>(ws);   // 627 one-wave blocks
  k_var   <<<nBlocksVar, 256, 0, stream>>>(pred, tgt, ws);
  k_vred  <<<2 * K_CLS, 256, 0, stream>>>(ws);             // 38 blocks
  k_final <<<1, 1024, 0, stream>>>(ws, out);
}

// Round 8
// 436.026 us; speedup vs baseline: 1.3382x; 1.0311x over previous
//
#include <hip/hip_runtime.h>

// HNM discriminative loss, MI355X — R11.
// predict (4,32,512,1024) f32, target (4,512,1024) i32 -> scalar f32.
// R11: budget audit across R0-R10 shows dur INCLUDES a ~159us harness ws
// re-poison fill in every round (fits all 10 totals within a few us; R0's
// "k_var=315" was a subtraction artifact — var was always ~155). Current:
// fill 159 + accum ~120 + var ~160 + tails ~10 = 449.6. Both kernels are
// ~3x their ~40-60us memory floor and both are occupancy/latency-starved:
//  - k_var: 72KB LDS -> 2 blocks/CU = 8 waves; 1-deep window pipeline stalls
//    ~900cy/window. Fix: 64px x 16ch half-windows -> 38KB LDS -> 4 blocks/CU
//    = 16 waves; counted vmcnt(4/5); sq/pos binned in REGISTERS (19 mask-adds
//    per PIXEL — cheap, unlike R6's per-px-ch mask-FMA); no LDS atomics.
//  - k_accum: dual-parity hist 39.4KB -> 4 blocks/CU. Fix: single-parity
//    19.8KB -> 8 blocks/CU = 32 waves (pre-reg: if worse, chain-ILP > TLP).

#define K_CLS 19
#define C_CH 32
#define HW_SHIFT 19            // H*W = 512*1024 = 2^19
#define HW_SIZE (1 << HW_SHIFT)
#define EPSF 1e-12f
#define THEA_F 0.5f
#define TWO_DELTA 3.0f
#define MIN_PIX 20.0f

// ---- ws float layout (no global atomics; every cell written before read) --
#define OFF_PSUM 0                       // [ch][64 slots][20] = 40960
#define OFF_PCNT 40960                   // [64 slots][20] = 1280
#define OFF_RED  42240                   // 608 sums + 19 counts (pad 640)
#define OFF_VRED 42880                   // 38 reduced sq/pos (pad 64)
#define OFF_VPART 42944                  // [1024 blk][64]: 19 sq + 19 pos
#define WS_FLOATS (OFF_VPART + 1024 * 64)

typedef const unsigned int __attribute__((address_space(1)))* GP;
typedef unsigned int __attribute__((address_space(3)))* LP;

__device__ __forceinline__ void atomAddF(float* p, float v) {
  unsafeAtomicAdd(p, v);       // cold paths only
}

// ---- Pass 1 v8: single-parity bank-per-lane histogram, 8 blocks/CU --------
// Blocks 0..2047: (plane, 16 slabs) feature sums. Blocks 2048..2111: counts.
__global__ __launch_bounds__(256) void k_accum(
    const float* __restrict__ pred, const int* __restrict__ tgt,
    float* __restrict__ ws)
{
  __shared__ float sA[4][K_CLS][64];            // 19456 B -> 8 blocks/CU
  __shared__ float s_w[4][20];
  const int t = threadIdx.x;
  const int w = t >> 6;
  const int lane = t & 63;
  float* colA = &sA[w][0][lane];                // colA[k<<6] = bin k, bank l%32
#pragma unroll
  for (int k = 0; k < K_CLS; ++k) colA[k << 6] = 0.f;

  if (blockIdx.x < 2048) {
    const int plane = blockIdx.x >> 4;       // 0..127
    const int slab  = blockIdx.x & 15;       // 0..15
    const int n_idx = plane >> 5;
    const int ch    = plane & 31;
    const float* pbase = pred + (((size_t)plane) << HW_SHIFT) + ((size_t)slab << 15);
    const int*   tbase = tgt  + (((size_t)n_idx) << HW_SHIFT) + ((size_t)slab << 15);

    float4 vA = *reinterpret_cast<const float4*>(pbase + t * 4);
    int4   cA = *reinterpret_cast<const int4*>(tbase + t * 4);
#pragma unroll 1
    for (int it = 0; it < 32; ++it) {
      float4 vB; int4 cB;
      if (it + 1 < 32) {
        vB = *reinterpret_cast<const float4*>(pbase + (it + 1) * 1024 + t * 4);
        cB = *reinterpret_cast<const int4*>(tbase + (it + 1) * 1024 + t * 4);
      }
      const float x[4] = {vA.x, vA.y, vA.z, vA.w};
      const int   s[4] = {cA.x, cA.y, cA.z, cA.w};
      const int   k0 = min((unsigned)s[0], 18u), k1 = min((unsigned)s[1], 18u);
      const int   k2 = min((unsigned)s[2], 18u), k3 = min((unsigned)s[3], 18u);
      const float v0 = ((unsigned)s[0] < K_CLS) ? x[0] : 0.f;
      const float v1 = ((unsigned)s[1] < K_CLS) ? x[1] : 0.f;
      const float v2 = ((unsigned)s[2] < K_CLS) ? x[2] : 0.f;
      const float v3 = ((unsigned)s[3] < K_CLS) ? x[3] : 0.f;
      colA[k0 << 6] += v0;
      colA[k1 << 6] += v1;
      colA[k2 << 6] += v2;
      colA[k3 << 6] += v3;
      vA = vB; cA = cB;
    }

    float acc[K_CLS];
#pragma unroll
    for (int k = 0; k < K_CLS; ++k) acc[k] = colA[k << 6];
#pragma unroll
    for (int k = 0; k < K_CLS; ++k) {
      float s = acc[k];
#pragma unroll
      for (int m = 1; m < 64; m <<= 1) s += __shfl_xor(s, m, 64);
      acc[k] = s;
    }
#pragma unroll
    for (int k = 0; k < K_CLS; ++k)
      if (lane == k) s_w[w][k] = acc[k];       // static index: no scratch
    __syncthreads();
    if (t < K_CLS) {
      const int slot = n_idx * 16 + slab;      // 0..63
      ws[OFF_PSUM + ch * (64 * 20) + slot * 20 + t] =
          s_w[0][t] + s_w[1][t] + s_w[2][t] + s_w[3][t];
    }
  } else {
    const int idx = blockIdx.x - 2048;       // 0..63
    const int n_idx = idx >> 4;
    const int slab  = idx & 15;
    const int* tbase = tgt + (((size_t)n_idx) << HW_SHIFT) + ((size_t)slab << 15);

#pragma unroll 1
    for (int it = 0; it < 32; ++it) {
      const int4 c4 = *reinterpret_cast<const int4*>(tbase + it * 1024 + t * 4);
      const int s[4] = {c4.x, c4.y, c4.z, c4.w};
      const int k0 = min((unsigned)s[0], 18u), k1 = min((unsigned)s[1], 18u);
      const int k2 = min((unsigned)s[2], 18u), k3 = min((unsigned)s[3], 18u);
      colA[k0 << 6] += ((unsigned)s[0] < K_CLS) ? 1.f : 0.f;
      colA[k1 << 6] += ((unsigned)s[1] < K_CLS) ? 1.f : 0.f;
      colA[k2 << 6] += ((unsigned)s[2] < K_CLS) ? 1.f : 0.f;
      colA[k3 << 6] += ((unsigned)s[3] < K_CLS) ? 1.f : 0.f;
    }

    float acc[K_CLS];
#pragma unroll
    for (int k = 0; k < K_CLS; ++k) acc[k] = colA[k << 6];
#pragma unroll
    for (int k = 0; k < K_CLS; ++k) {
      float s = acc[k];
#pragma unroll
      for (int m = 1; m < 64; m <<= 1) s += __shfl_xor(s, m, 64);
      acc[k] = s;
    }
#pragma unroll
    for (int k = 0; k < K_CLS; ++k)
      if (lane == k) s_w[w][k] = acc[k];
    __syncthreads();
    if (t < K_CLS) {
      const int slot = n_idx * 16 + slab;
      ws[OFF_PCNT + slot * 20 + t] = s_w[0][t] + s_w[1][t] + s_w[2][t] + s_w[3][t];
    }
  }
}

// ---- Reduce: 627 one-wave blocks, lane = slot ----------------------------
__global__ __launch_bounds__(64) void k_reduce(float* __restrict__ ws)
{
  const int o = blockIdx.x;            // 0..626
  const int lane = threadIdx.x;        // 0..63 = slot
  float a;
  if (o < C_CH * K_CLS) {
    const int ch = o / K_CLS, k = o - ch * K_CLS;
    a = ws[OFF_PSUM + ch * (64 * 20) + lane * 20 + k];
  } else {
    a = ws[OFF_PCNT + lane * 20 + (o - C_CH * K_CLS)];
  }
#pragma unroll
  for (int m = 1; m < 64; m <<= 1) a += __shfl_xor(a, m, 64);
  if (lane == 0) ws[OFF_RED + o] = a;
}

// ---- Pass 2 v5: 64px x 16ch half-windows, 16 waves/CU, register bins ------
// Block = 2048 px (4 waves x 512). Per wave: 8 px-windows x 2 ch-halves =
// 16 stages; stage = 4 gload_lds (+1 cls on even). vmcnt(4/5) counted.
__global__ __launch_bounds__(256) void k_var(
    const float* __restrict__ pred, const int* __restrict__ tgt,
    float* __restrict__ ws)
{
  __shared__ float s_buf[4][2][16][64];     // 32 KB
  __shared__ int   s_cls[4][2][64];         // 2 KB
  __shared__ float s_ctr[C_CH][K_CLS];      // 2.4 KB
  __shared__ float s_w[4][40];              // flush combine

  const int t = threadIdx.x;
  const int w = t >> 6;
  const int lane = t & 63;

  for (int i = t; i < C_CH * K_CLS; i += 256) {
    const int k = i % K_CLS;
    (&s_ctr[0][0])[i] = ws[OFF_RED + i] / fmaxf(ws[OFF_RED + C_CH * K_CLS + k], 1.f);
  }
  __syncthreads();

  const size_t P0 = (size_t)blockIdx.x * 2048;
  const int n_idx = (int)(P0 >> HW_SHIFT);
  const int hw0 = (int)(P0 & (HW_SIZE - 1));

#define VSTAGE(s_)                                                            \
  {                                                                           \
    const int p_ = (s_) & 1, pxw_ = (s_) >> 1;                                \
    const int pw_ = hw0 + w * 512 + pxw_ * 64;                                \
    const int cb_ = p_ * 16;                                                  \
    _Pragma("unroll")                                                         \
    for (int q = 0; q < 4; ++q) {                                             \
      const int ch_ = cb_ + q * 4 + (lane >> 4);                              \
      const float* gp = pred + (((size_t)(n_idx * C_CH + ch_)) << HW_SHIFT)   \
                        + pw_ + (lane & 15) * 4;                              \
      __builtin_amdgcn_global_load_lds((GP)gp, (LP)&s_buf[w][p_][q * 4][0],   \
                                       16, 0, 0);                             \
    }                                                                         \
    if (p_ == 0 && lane < 16) {                                               \
      const int* gt = tgt + (((size_t)n_idx) << HW_SHIFT) + pw_ + lane * 4;   \
      __builtin_amdgcn_global_load_lds((GP)gt, (LP)&s_cls[w][pxw_ & 1][0],    \
                                       16, 0, 0);                             \
    }                                                                         \
  }

  float acc_sq[K_CLS], acc_pos[K_CLS];
#pragma unroll
  for (int k = 0; k < K_CLS; ++k) { acc_sq[k] = 0.f; acc_pos[k] = 0.f; }

  int  ci = 0, sc = 0;
  bool vld = false;
  float d2 = 0.f;

  VSTAGE(0)
#pragma unroll 1
  for (int s = 0; s < 16; ++s) {
    if (s < 15) {
      VSTAGE(s + 1)
      // wait for stage s's loads: stage s+1 has 4 (odd) or 5 (even) in flight
      if (s & 1) asm volatile("s_waitcnt vmcnt(5)" ::: "memory");
      else       asm volatile("s_waitcnt vmcnt(4)" ::: "memory");
    } else {
      asm volatile("s_waitcnt vmcnt(0)" ::: "memory");
    }
    __builtin_amdgcn_sched_barrier(0);

    const int p = s & 1, pxw = s >> 1, cb = p * 16;
    if (p == 0) {
      ci = s_cls[w][pxw & 1][lane];
      vld = (unsigned)ci < K_CLS;
      sc = vld ? ci : 0;
      d2 = 0.f;
    }
#pragma unroll
    for (int cc = 0; cc < 16; ++cc) {
      const float x = s_buf[w][p][cc][lane];   // bank lane%32: conflict-free
      const float d = s_ctr[cb + cc][sc] - x;  // 19-word row: bcast/distinct-bank
      d2 = fmaf(d, d, d2);
    }
    if (p == 1) {
      const float r = sqrtf(d2 + EPSF) - THEA_F;
      const bool act = vld && (r > 0.f);
      const float rr = act ? r * r : 0.f;
      const float pp = act ? 1.f : 0.f;
#pragma unroll
      for (int k = 0; k < K_CLS; ++k) {
        const bool b = (sc == k);
        acc_sq[k]  += b ? rr : 0.f;
        acc_pos[k] += b ? pp : 0.f;
      }
    }
  }
#undef VSTAGE

  // flush: wave shfl reduce -> 4-wave combine -> vpart
#pragma unroll
  for (int k = 0; k < K_CLS; ++k) {
    float a = acc_sq[k], b = acc_pos[k];
#pragma unroll
    for (int m = 1; m < 64; m <<= 1) {
      a += __shfl_xor(a, m, 64);
      b += __shfl_xor(b, m, 64);
    }
    acc_sq[k] = a; acc_pos[k] = b;
  }
#pragma unroll
  for (int k = 0; k < K_CLS; ++k)
    if (lane == k) { s_w[w][k] = acc_sq[k]; s_w[w][20 + k] = acc_pos[k]; }
  __syncthreads();
  if (t < K_CLS) {
    float* vp = ws + OFF_VPART + (size_t)blockIdx.x * 64;
    vp[t]         = s_w[0][t] + s_w[1][t] + s_w[2][t] + s_w[3][t];
    vp[K_CLS + t] = s_w[0][20 + t] + s_w[1][20 + t] + s_w[2][20 + t] + s_w[3][20 + t];
  }
}

// ---- Pre-reduce sq/pos: 38 blocks x 256 threads ---------------------------
__global__ __launch_bounds__(256) void k_vred(float* __restrict__ ws)
{
  const int o = blockIdx.x;            // 0..37 (sq: 0..18, pos: 19..37)
  const int t = threadIdx.x;
  float a = 0.f;
#pragma unroll
  for (int r = 0; r < 4; ++r)
    a += ws[OFF_VPART + (size_t)(t + r * 256) * 64 + o];
#pragma unroll
  for (int m = 1; m < 64; m <<= 1) a += __shfl_xor(a, m, 64);
  __shared__ float s[4];
  if ((t & 63) == 0) s[t >> 6] = a;
  __syncthreads();
  if (t == 0) ws[OFF_VRED + o] = s[0] + s[1] + s[2] + s[3];
}

// ---- Finalize: loss_var + loss_dis + 0.001*loss_reg -----------------------
__global__ __launch_bounds__(1024) void k_final(
    float* __restrict__ ws, float* __restrict__ out)
{
  __shared__ float s_ctr[C_CH * K_CLS];
  __shared__ float s_valid[K_CLS];
  __shared__ float s_red[3];
  __shared__ float s_ncls;
  const int t = threadIdx.x;
  if (t < 3) s_red[t] = 0.f;
  if (t < K_CLS) s_valid[t] = (ws[OFF_RED + C_CH * K_CLS + t] > MIN_PIX) ? 1.f : 0.f;
  for (int i = t; i < C_CH * K_CLS; i += 1024) {
    const int k = i % K_CLS;
    s_ctr[i] = ws[OFF_RED + i] / fmaxf(ws[OFF_RED + C_CH * K_CLS + k], 1.f);
  }
  __syncthreads();

  if (t == 0) {
    float n = 0.f;
    for (int k = 0; k < K_CLS; ++k) n += s_valid[k];
    s_ncls = fmaxf(n, 1.f);
  }
  if (t < K_CLS && s_valid[t] > 0.f) {
    const float sq  = ws[OFF_VRED + t];
    const float pos = ws[OFF_VRED + K_CLS + t];
    atomAddF(&s_red[0], sq / fmaxf(pos, 1.f));
    float nn = 0.f;
#pragma unroll
    for (int ch = 0; ch < C_CH; ++ch) {
      const float cv = s_ctr[ch * K_CLS + t];
      nn = fmaf(cv, cv, nn);
    }
    atomAddF(&s_red[2], sqrtf(nn + EPSF));
  }
  if (t < K_CLS * K_CLS) {
    const int a = t / K_CLS, b = t - (t / K_CLS) * K_CLS;
    if (a != b && s_valid[a] > 0.f && s_valid[b] > 0.f) {
      float dd = 0.f;
#pragma unroll
      for (int ch = 0; ch < C_CH; ++ch) {
        const float df = s_ctr[ch * K_CLS + a] - s_ctr[ch * K_CLS + b];
        dd = fmaf(df, df, dd);
      }
      const float dist = sqrtf(dd + EPSF);
      const float d = fmaxf(TWO_DELTA - dist, 0.f);
      if (d > 0.f) atomAddF(&s_red[1], d * d);
    }
  }
  __syncthreads();
  if (t == 0) {
    const float n = s_ncls;
    out[0] = s_red[0] / n
           + s_red[1] / fmaxf(n * (n - 1.f), 1.f)
           + 0.001f * s_red[2] / n;
  }
}

extern "C" void kernel_launch(void* const* d_in, const int* in_sizes, int n_in,
                              void* d_out, int out_size, void* d_ws, size_t ws_size,
                              hipStream_t stream) {
  const float* pred = (const float*)d_in[0];
  const int*   tgt  = (const int*)d_in[1];
  float* ws  = (float*)d_ws;
  float* out = (float*)d_out;
  const int P = in_sizes[1];            // n*h*w = 2097152
  const int nBlocksVar = P / 2048;      // 1024

  k_accum <<<2048 + 64, 256, 0, stream>>>(pred, tgt, ws);  // 2048 sum + 64 count
  k_reduce<<<C_CH * K_CLS + K_CLS, 64, 0, stream>>>(ws);   // 627 one-wave blocks
  k_var   <<<nBlocksVar, 256, 0, stream>>>(pred, tgt, ws);
  k_vred  <<<2 * K_CLS, 256, 0, stream>>>(ws);             // 38 blocks
  k_final <<<1, 1024, 0, stream>>>(ws, out);
}